// Round 3
// baseline (38.503 us; speedup 1.0000x reference)
//
#include <hip/hip_runtime.h>
#include <hip/hip_bf16.h>

// MaskedDenseLayer via grouped bf16 MFMA, round 3: latency-hiding restructure.
// out[b,o] = relu(sum_i x[b,i] * kernel[i,o] * masks[state[b],i,o] + b0[o])
//
// Grid: 512 blocks = (state 16) x (o-tile 32 of 32 cols) -> 2 blocks/CU.
// Block: 512 thr = 8 waves = (kh: k-half) x (nsl: 16-col slice) x (mq: m-frag).
// -> 16 waves/CU (4/SIMD), every wave load-balanced (ns ~= 32 -> 2 m-frags).
// Per wave: mfma_f32_16x16x32_bf16, acc[2] m-frags (rows base+mq*16, +32),
// K-half = 392 = 12 steps of 32 + 8-tail (lg==0 only).
// A: lane row=l15, k=8*lg+e -> 2 float4 loads from gathered x row.
// B: lane col=l15, k=8*lg+e -> 8+8 strided dwords of kern/mask, product, cvt.
// k-halves reduced through LDS [4][2][4][64] (lane-contiguous, conflict-free).

#define BS 512
#define IN_DIM 784
#define OUT_DIM 1024
#define N_MASKS 16
#define KHALF 392          // per k-half
#define KSTEPS 12          // full 32-wide steps per half (+8 tail)

typedef __attribute__((ext_vector_type(8))) short bf16x8;
typedef __attribute__((ext_vector_type(4))) float f32x4;

static __device__ inline short f2bf(float f) {
    __hip_bfloat16 h = __float2bfloat16(f);   // RNE
    short r; __builtin_memcpy(&r, &h, 2); return r;
}

__global__ __launch_bounds__(512, 2) void made_mfma3(
    const float* __restrict__ x,      // [BS, IN_DIM]
    const int*   __restrict__ state,  // [BS]
    const float* __restrict__ masks,  // [N_MASKS, IN_DIM, OUT_DIM]
    const float* __restrict__ kern,   // [IN_DIM, OUT_DIM]
    const float* __restrict__ bias,   // [OUT_DIM]
    float*       __restrict__ out)    // [BS, OUT_DIM]
{
    __shared__ int   list[BS];
    __shared__ int   cnt;
    __shared__ float red[4][2][4][64];   // [nsl*2+mq][mfrag][reg][lane] 8 KB

    const int tid  = threadIdx.x;
    const int s    = blockIdx.x >> 5;    // state 0..15
    const int ot   = blockIdx.x & 31;    // o-tile 0..31 (32 cols each)
    const int lane = tid & 63;
    const int w    = tid >> 6;
    const int mq   = w & 1;
    const int nsl  = (w >> 1) & 1;
    const int kh   = w >> 2;             // 0..1

    if (tid == 0) cnt = 0;
    __syncthreads();
    { int st = state[tid]; if (st == s) { int p = atomicAdd(&cnt, 1); list[p] = tid; } }
    __syncthreads();
    const int ns = cnt;

    const int l15 = lane & 15;
    const int lg  = lane >> 4;                 // k-subgroup 0..3
    const int col = ot * 32 + nsl * 16 + l15;  // this lane's output column

    // B base: row kh*392 + lg*8, this col
    const size_t brow0 = (size_t)(kh * KHALF + lg * 8) * OUT_DIM + col;
    const float* kp = kern + brow0;
    const float* mp = masks + (size_t)s * IN_DIM * OUT_DIM + brow0;
    const int xk0 = kh * KHALF + lg * 8;       // A k-offset for this lane

    for (int base = 0; base < ns; base += 64) {
        int r0 = base + mq * 16 + l15;       if (r0 >= ns) r0 = ns - 1;
        int r1 = base + 32 + mq * 16 + l15;  if (r1 >= ns) r1 = ns - 1;
        const float* xr0 = x + (size_t)list[r0] * IN_DIM + xk0;
        const float* xr1 = x + (size_t)list[r1] * IN_DIM + xk0;

        f32x4 acc0, acc1;
#pragma unroll
        for (int r = 0; r < 4; ++r) { acc0[r] = 0.f; acc1[r] = 0.f; }

#pragma unroll 4
        for (int stp = 0; stp < KSTEPS; ++stp) {
            const int k0 = stp * 32;
            bf16x8 a0, a1, b;
            {
                float4 pa = *(const float4*)(xr0 + k0);
                float4 pb = *(const float4*)(xr0 + k0 + 4);
                a0[0]=f2bf(pa.x); a0[1]=f2bf(pa.y); a0[2]=f2bf(pa.z); a0[3]=f2bf(pa.w);
                a0[4]=f2bf(pb.x); a0[5]=f2bf(pb.y); a0[6]=f2bf(pb.z); a0[7]=f2bf(pb.w);
                float4 qa = *(const float4*)(xr1 + k0);
                float4 qb = *(const float4*)(xr1 + k0 + 4);
                a1[0]=f2bf(qa.x); a1[1]=f2bf(qa.y); a1[2]=f2bf(qa.z); a1[3]=f2bf(qa.w);
                a1[4]=f2bf(qb.x); a1[5]=f2bf(qb.y); a1[6]=f2bf(qb.z); a1[7]=f2bf(qb.w);
            }
#pragma unroll
            for (int e = 0; e < 8; ++e) {
                size_t off = (size_t)(k0 + e) * OUT_DIM;
                b[e] = f2bf(kp[off] * mp[off]);
            }
            acc0 = __builtin_amdgcn_mfma_f32_16x16x32_bf16(a0, b, acc0, 0, 0, 0);
            acc1 = __builtin_amdgcn_mfma_f32_16x16x32_bf16(a1, b, acc1, 0, 0, 0);
        }

        {   // 8-wide tail: k = kh*392 + 384 .. +391, only lg==0 contributes
            bf16x8 a0, a1, b;
#pragma unroll
            for (int e = 0; e < 8; ++e) { a0[e]=0; a1[e]=0; b[e]=0; }
            if (lg == 0) {
                const int k0 = KSTEPS * 32;   // 384
                float4 pa = *(const float4*)(xr0 + k0);
                float4 pb = *(const float4*)(xr0 + k0 + 4);
                a0[0]=f2bf(pa.x); a0[1]=f2bf(pa.y); a0[2]=f2bf(pa.z); a0[3]=f2bf(pa.w);
                a0[4]=f2bf(pb.x); a0[5]=f2bf(pb.y); a0[6]=f2bf(pb.z); a0[7]=f2bf(pb.w);
                float4 qa = *(const float4*)(xr1 + k0);
                float4 qb = *(const float4*)(xr1 + k0 + 4);
                a1[0]=f2bf(qa.x); a1[1]=f2bf(qa.y); a1[2]=f2bf(qa.z); a1[3]=f2bf(qa.w);
                a1[4]=f2bf(qb.x); a1[5]=f2bf(qb.y); a1[6]=f2bf(qb.z); a1[7]=f2bf(qb.w);
#pragma unroll
                for (int e = 0; e < 8; ++e) {
                    size_t off = (size_t)(k0 + e) * OUT_DIM;
                    b[e] = f2bf(kp[off] * mp[off]);
                }
            }
            acc0 = __builtin_amdgcn_mfma_f32_16x16x32_bf16(a0, b, acc0, 0, 0, 0);
            acc1 = __builtin_amdgcn_mfma_f32_16x16x32_bf16(a1, b, acc1, 0, 0, 0);
        }

        // ---- reduce k-halves ----
        const int ridx = nsl * 2 + mq;
        if (kh == 1) {
#pragma unroll
            for (int r = 0; r < 4; ++r) {
                red[ridx][0][r][lane] = acc0[r];
                red[ridx][1][r][lane] = acc1[r];
            }
        }
        __syncthreads();
        if (kh == 0) {
#pragma unroll
            for (int m = 0; m < 2; ++m) {
#pragma unroll
                for (int r = 0; r < 4; ++r) {
                    float v = (m == 0 ? acc0[r] : acc1[r]) + red[ridx][m][r][lane];
                    int sr = base + m * 32 + mq * 16 + lg * 4 + r;
                    if (sr < ns) {
                        int b = list[sr];
                        v += bias[col];
                        out[(size_t)b * OUT_DIM + col] = v > 0.f ? v : 0.f;
                    }
                }
            }
        }
        __syncthreads();   // red[] reused next m-chunk
    }
}

extern "C" void kernel_launch(void* const* d_in, const int* in_sizes, int n_in,
                              void* d_out, int out_size, void* d_ws, size_t ws_size,
                              hipStream_t stream) {
    const float* x     = (const float*)d_in[0];
    const int*   state = (const int*)  d_in[1];
    const float* masks = (const float*)d_in[2];
    const float* kern  = (const float*)d_in[3];
    const float* b0    = (const float*)d_in[4];
    float* out = (float*)d_out;

    made_mfma3<<<dim3(512), dim3(512), 0, stream>>>(x, state, masks, kern, b0, out);
}

// Round 4
// 33.601 us; speedup vs baseline: 1.1459x; 1.1459x over previous
//
#include <hip/hip_runtime.h>
#include <hip/hip_bf16.h>

// MaskedDenseLayer via grouped bf16 MFMA, round 4: explicit 2-deep register
// pipeline (the round-3 post-mortem showed VGPR=52 -> compiler never
// software-pipelined; every K-step drained its loads serially).
//
// Grid: 512 blocks = (state 16) x (o-tile 32 of 32 cols), 2 blocks/CU.
// Block: 512 thr = 8 waves = (kh k-half) x (nsl 16-col slice) x (mq m-frag).
// m-chunk = 32 rows, 1 m-frag (16 rows) per wave -> no wasted MFMA work.
// Per wave: 12 x 32-wide K-steps + 8-wide tail, mfma_f32_16x16x32_bf16.
// Pipeline: two named register sets s0/s1; issue step t+2's 18 loads right
// after converting step t's registers to fragments, before the MFMA.
// A: lane row=l15, 2x float4 from gathered x row. B: 8 kern + 8 mask dwords
// at 4KB stride, w = k*m -> bf16. k-halves reduced via LDS (conflict-free).

#define BS 512
#define IN_DIM 784
#define OUT_DIM 1024
#define N_MASKS 16
#define KHALF 392
#define KSTEPS 12          // full 32-wide steps per half (+8-wide tail)

typedef __attribute__((ext_vector_type(8))) short bf16x8;
typedef __attribute__((ext_vector_type(4))) float f32x4;

static __device__ inline short f2bf(float f) {
    __hip_bfloat16 h = __float2bfloat16(f);   // RNE
    short r; __builtin_memcpy(&r, &h, 2); return r;
}

struct LoadSet {
    float4 xa, xb;      // A: 8 f32 of this lane's x row
    float  kv[8];       // kernel dwords
    float  mv[8];       // mask dwords
};

static __device__ inline void issue_loads(LoadSet& S, const float* __restrict__ xr,
                                          const float* __restrict__ kp,
                                          const float* __restrict__ mp, int k0) {
    S.xa = *(const float4*)(xr + k0);
    S.xb = *(const float4*)(xr + k0 + 4);
#pragma unroll
    for (int e = 0; e < 8; ++e) {
        size_t off = (size_t)(k0 + e) * OUT_DIM;
        S.kv[e] = kp[off];
        S.mv[e] = mp[off];
    }
}

static __device__ inline void make_frags(const LoadSet& S, bf16x8& a, bf16x8& b) {
    a[0]=f2bf(S.xa.x); a[1]=f2bf(S.xa.y); a[2]=f2bf(S.xa.z); a[3]=f2bf(S.xa.w);
    a[4]=f2bf(S.xb.x); a[5]=f2bf(S.xb.y); a[6]=f2bf(S.xb.z); a[7]=f2bf(S.xb.w);
#pragma unroll
    for (int e = 0; e < 8; ++e) b[e] = f2bf(S.kv[e] * S.mv[e]);
}

__global__ __launch_bounds__(512, 2) void made_mfma4(
    const float* __restrict__ x,      // [BS, IN_DIM]
    const int*   __restrict__ state,  // [BS]
    const float* __restrict__ masks,  // [N_MASKS, IN_DIM, OUT_DIM]
    const float* __restrict__ kern,   // [IN_DIM, OUT_DIM]
    const float* __restrict__ bias,   // [OUT_DIM]
    float*       __restrict__ out)    // [BS, OUT_DIM]
{
    __shared__ int   list[BS];
    __shared__ int   cnt;
    __shared__ float red[4][4][64];   // [nsl*2+mq][reg][lane] 4 KB

    const int tid  = threadIdx.x;
    const int s    = blockIdx.x >> 5;    // state
    const int ot   = blockIdx.x & 31;    // o-tile (32 cols)
    const int lane = tid & 63;
    const int w    = tid >> 6;
    const int mq   = w & 1;
    const int nsl  = (w >> 1) & 1;
    const int kh   = w >> 2;

    if (tid == 0) cnt = 0;
    __syncthreads();
    { int st = state[tid]; if (st == s) { int p = atomicAdd(&cnt, 1); list[p] = tid; } }
    __syncthreads();
    const int ns = cnt;

    const int l15 = lane & 15;
    const int lg  = lane >> 4;                 // k-subgroup 0..3
    const int col = ot * 32 + nsl * 16 + l15;

    const size_t brow0 = (size_t)(kh * KHALF + lg * 8) * OUT_DIM + col;
    const float* kp = kern + brow0;
    const float* mp = masks + (size_t)s * IN_DIM * OUT_DIM + brow0;
    const int xk0 = kh * KHALF + lg * 8;
    const int tclamp = (lg == 0) ? KSTEPS * 32 : 0;   // tail offset, OOB-safe
    const float biasv = bias[col];

    for (int base = 0; base < ns; base += 32) {
        int r0 = base + mq * 16 + l15; if (r0 >= ns) r0 = ns - 1;
        const float* xr = x + (size_t)list[r0] * IN_DIM + xk0;

        f32x4 acc;
#pragma unroll
        for (int r = 0; r < 4; ++r) acc[r] = 0.f;

        LoadSet s0, s1;
        issue_loads(s0, xr, kp, mp, 0);
        issue_loads(s1, xr, kp, mp, 32);

#pragma unroll
        for (int p = 0; p < 5; ++p) {       // steps 0..9, loads through step 11
            bf16x8 a, b;
            make_frags(s0, a, b);
            issue_loads(s0, xr, kp, mp, (2 * p + 2) * 32);
            acc = __builtin_amdgcn_mfma_f32_16x16x32_bf16(a, b, acc, 0, 0, 0);
            make_frags(s1, a, b);
            issue_loads(s1, xr, kp, mp, (2 * p + 3) * 32);
            acc = __builtin_amdgcn_mfma_f32_16x16x32_bf16(a, b, acc, 0, 0, 0);
        }
        {   // step 10; issue tail loads (clamped for lg>0, zeroed below)
            bf16x8 a, b;
            make_frags(s0, a, b);
            issue_loads(s0, xr, kp, mp, tclamp);
            acc = __builtin_amdgcn_mfma_f32_16x16x32_bf16(a, b, acc, 0, 0, 0);
        }
        {   // step 11
            bf16x8 a, b;
            make_frags(s1, a, b);
            acc = __builtin_amdgcn_mfma_f32_16x16x32_bf16(a, b, acc, 0, 0, 0);
        }
        {   // tail: k = 384..391 of this half, only lg==0 contributes
            bf16x8 a, b;
            make_frags(s0, a, b);
            if (lg != 0) {
#pragma unroll
                for (int e = 0; e < 8; ++e) { a[e] = 0; b[e] = 0; }
            }
            acc = __builtin_amdgcn_mfma_f32_16x16x32_bf16(a, b, acc, 0, 0, 0);
        }

        // ---- reduce k-halves, store ----
        const int ridx = nsl * 2 + mq;
        if (kh == 1) {
#pragma unroll
            for (int r = 0; r < 4; ++r) red[ridx][r][lane] = acc[r];
        }
        __syncthreads();
        if (kh == 0) {
#pragma unroll
            for (int r = 0; r < 4; ++r) {
                float v = acc[r] + red[ridx][r][lane];
                int sr = base + mq * 16 + lg * 4 + r;
                if (sr < ns) {
                    int b = list[sr];
                    v += biasv;
                    out[(size_t)b * OUT_DIM + col] = v > 0.f ? v : 0.f;
                }
            }
        }
        __syncthreads();   // red[] reused next m-chunk
    }
}

extern "C" void kernel_launch(void* const* d_in, const int* in_sizes, int n_in,
                              void* d_out, int out_size, void* d_ws, size_t ws_size,
                              hipStream_t stream) {
    const float* x     = (const float*)d_in[0];
    const int*   state = (const int*)  d_in[1];
    const float* masks = (const float*)d_in[2];
    const float* kern  = (const float*)d_in[3];
    const float* b0    = (const float*)d_in[4];
    float* out = (float*)d_out;

    made_mfma4<<<dim3(512), dim3(512), 0, stream>>>(x, state, masks, kern, b0, out);
}

// Round 5
// 28.337 us; speedup vs baseline: 1.3588x; 1.1858x over previous
//
#include <hip/hip_runtime.h>
#include <hip/hip_bf16.h>

// MaskedDenseLayer round 5: grouped GEMM, LDS-staged via global_load_lds
// (async, no VGPR round-trip -- the only pipelining hipcc preserves, m97
// structure), mfma_f32_32x32x16_bf16 (M=32 covers the whole state group).
//
// kernel1: grid 1024 = (state 16) x (otile 32 of 32 cols) x (khalf 2: 400/384)
//   -> 4 blocks/CU, 16 waves/CU (4/SIMD). Block 256 thr = 4 waves, wave w
//   owns 16-k slice of each BK=64 stage. Per stage: issue 4 global_load_lds
//   dwordx4 (kern+mask f32 tiles, rows packed [64][32], 1KB/instr), one
//   __syncthreads (compiler drains vmcnt there -> tile ready), consume:
//   16 ds_read_b32 (col==bank -> conflict-free) + mul + cvt + 1-2 MFMA.
//   K-halves go to out (kh0) / ws (kh1); 4-wave distributed reduce via
//   LDS aliased over the tiles.
// kernel2: out = relu(out + ws + bias), float4 elementwise.

#define IN_DIM 784
#define OUT_DIM 1024

typedef __attribute__((ext_vector_type(8))) short bf16x8;
typedef __attribute__((ext_vector_type(4))) float f32x4;
typedef __attribute__((ext_vector_type(16))) float f32x16;

static __device__ inline short f2bf(float f) {
    __hip_bfloat16 h = __float2bfloat16(f);   // RNE
    short r; __builtin_memcpy(&r, &h, 2); return r;
}

static __device__ inline void gload_lds16(const float* g, void* l) {
    __builtin_amdgcn_global_load_lds(
        (const __attribute__((address_space(1))) void*)g,
        (__attribute__((address_space(3))) void*)l, 16, 0, 0);
}

static __device__ inline bf16x8 pack8(float4 a, float4 b) {
    bf16x8 r;
    r[0]=f2bf(a.x); r[1]=f2bf(a.y); r[2]=f2bf(a.z); r[3]=f2bf(a.w);
    r[4]=f2bf(b.x); r[5]=f2bf(b.y); r[6]=f2bf(b.z); r[7]=f2bf(b.w);
    return r;
}

__global__ __launch_bounds__(256, 4) void made_k1(
    const float* __restrict__ x,      // [512, 784]
    const int*   __restrict__ state,  // [512]
    const float* __restrict__ masks,  // [16, 784, 1024]
    const float* __restrict__ kern,   // [784, 1024]
    float*       __restrict__ out0,   // [512, 1024] (kh=0 partial)
    float*       __restrict__ ws1)    // [512, 1024] (kh=1 partial)
{
    __shared__ float tiles[2][2][64][32];   // [buf][kern/mask][row][col] 32 KB
    __shared__ int   list[512];
    __shared__ int   cnt;

    const int tid  = threadIdx.x;
    const int lane = tid & 63;
    const int w    = tid >> 6;            // wave 0..3 = 16-k slice owner
    const int bid  = blockIdx.x;
    const int s    = bid & 15;
    const int ot   = (bid >> 4) & 31;
    const int kh   = bid >> 9;            // 0/1
    const int oc0  = ot * 32;
    const int k00  = kh ? 400 : 0;
    const int NS   = kh ? 6 : 7;          // stages (kh0 stage 6 has 16 rows)

    if (tid == 0) cnt = 0;
    __syncthreads();
    {
        int st = state[tid];
        if (st == s) { int p = atomicAdd(&cnt, 1); list[p] = tid; }
        int st2 = state[tid + 256];
        if (st2 == s) { int p = atomicAdd(&cnt, 1); list[p] = tid + 256; }
    }

    const float* mS = masks + (size_t)s * (IN_DIM * (size_t)OUT_DIM);

    auto stage = [&](int t, int buf) {
        const int R   = (kh == 0 && t == 6) ? 16 : 64;
        const int gk0 = k00 + t * 64;
#pragma unroll
        for (int p = 0; p < 2; ++p) {
            int r0 = w * 16 + p * 8;
            if (r0 < R) {
                int gr = gk0 + r0 + (lane >> 3);
                size_t go = (size_t)gr * OUT_DIM + oc0 + (lane & 7) * 4;
                gload_lds16(kern + go, (void*)&tiles[buf][0][r0][0]);
                gload_lds16(mS   + go, (void*)&tiles[buf][1][r0][0]);
            }
        }
    };

    stage(0, 0);
    __syncthreads();                      // list + stage0 both ready
    const int ns  = cnt;
    const bool two = ns > 32;

    const int l31 = lane & 31;
    const int khl = (lane >> 5) * 8;      // k sub-offset within 16-k slice

    auto rowof = [&](int idx) -> int {
        if (ns == 0) return 0;
        return list[idx < ns ? idx : ns - 1];
    };
    const float* xr0 = x + (size_t)rowof(l31) * IN_DIM;
    const float* xr1 = x + (size_t)rowof(32 + l31) * IN_DIM;

    f32x16 acc0, acc1;
#pragma unroll
    for (int r = 0; r < 16; ++r) { acc0[r] = 0.f; acc1[r] = 0.f; }

    int buf = 0;
    for (int t = 0; t < NS; ++t) {
        if (t + 1 < NS) stage(t + 1, buf ^ 1);   // async into other buffer
        const int R = (kh == 0 && t == 6) ? 16 : 64;
        if (w * 16 < R) {
            const int kb_ = w * 16 + khl;        // row in tile
            bf16x8 bfr;
#pragma unroll
            for (int e = 0; e < 8; ++e) {
                float kv = tiles[buf][0][kb_ + e][l31];
                float mv = tiles[buf][1][kb_ + e][l31];
                bfr[e] = f2bf(kv * mv);
            }
            const int gk = k00 + t * 64 + kb_;   // global k for A loads
            {
                float4 xa = *(const float4*)(xr0 + gk);
                float4 xb = *(const float4*)(xr0 + gk + 4);
                acc0 = __builtin_amdgcn_mfma_f32_32x32x16_bf16(pack8(xa, xb), bfr, acc0, 0, 0, 0);
            }
            if (two) {
                float4 xa = *(const float4*)(xr1 + gk);
                float4 xb = *(const float4*)(xr1 + gk + 4);
                acc1 = __builtin_amdgcn_mfma_f32_32x32x16_bf16(pack8(xa, xb), bfr, acc1, 0, 0, 0);
            }
        }
        __syncthreads();                  // stage t+1 arrived; buf reusable
        buf ^= 1;
    }

    // ---- distributed 4-way K-slice reduce (LDS aliased over tiles) ----
    // red[c][owner 4][writer 3][lane 64][4] f32 = 24 KB
    float (*red)[4][3][64][4] = (float (*)[4][3][64][4])tiles;
#pragma unroll
    for (int o = 0; o < 4; ++o) {
        if (o == w) continue;
        int wi = (w < o) ? w : w - 1;
        f32x4 v0, v1;
#pragma unroll
        for (int j = 0; j < 4; ++j) { v0[j] = acc0[o * 4 + j]; v1[j] = acc1[o * 4 + j]; }
        *(f32x4*)&red[0][o][wi][lane][0] = v0;
        if (two) *(f32x4*)&red[1][o][wi][lane][0] = v1;
    }
    __syncthreads();

    float* dst = kh ? ws1 : out0;
    {
        f32x4 s0;
#pragma unroll
        for (int j = 0; j < 4; ++j) s0[j] = acc0[w * 4 + j];
#pragma unroll
        for (int q = 0; q < 3; ++q) s0 += *(f32x4*)&red[0][w][q][lane][0];
#pragma unroll
        for (int j = 0; j < 4; ++j) {
            int r = j + 8 * w + 4 * (lane >> 5);     // C row (m74/m101 layout)
            if (r < ns) dst[(size_t)list[r] * OUT_DIM + oc0 + l31] = s0[j];
        }
        if (two) {
            f32x4 s1;
#pragma unroll
            for (int j = 0; j < 4; ++j) s1[j] = acc1[w * 4 + j];
#pragma unroll
            for (int q = 0; q < 3; ++q) s1 += *(f32x4*)&red[1][w][q][lane][0];
#pragma unroll
            for (int j = 0; j < 4; ++j) {
                int r = 32 + j + 8 * w + 4 * (lane >> 5);
                if (r < ns) dst[(size_t)list[r] * OUT_DIM + oc0 + l31] = s1[j];
            }
        }
    }
}

__global__ __launch_bounds__(256) void made_k2(
    const float* __restrict__ ws, const float* __restrict__ bias,
    float* __restrict__ out)
{
    int i = blockIdx.x * 256 + threadIdx.x;        // 131072 float4s
    float4 a = ((const float4*)out)[i];
    float4 b = ((const float4*)ws)[i];
    float4 c = ((const float4*)bias)[i & 255];     // 1024 f32 = 256 float4
    float4 v;
    v.x = a.x + b.x + c.x; v.y = a.y + b.y + c.y;
    v.z = a.z + b.z + c.z; v.w = a.w + b.w + c.w;
    v.x = v.x > 0.f ? v.x : 0.f; v.y = v.y > 0.f ? v.y : 0.f;
    v.z = v.z > 0.f ? v.z : 0.f; v.w = v.w > 0.f ? v.w : 0.f;
    ((float4*)out)[i] = v;
}

extern "C" void kernel_launch(void* const* d_in, const int* in_sizes, int n_in,
                              void* d_out, int out_size, void* d_ws, size_t ws_size,
                              hipStream_t stream) {
    (void)in_sizes; (void)n_in; (void)out_size; (void)ws_size;
    const float* x     = (const float*)d_in[0];
    const int*   state = (const int*)  d_in[1];
    const float* masks = (const float*)d_in[2];
    const float* kern  = (const float*)d_in[3];
    const float* b0    = (const float*)d_in[4];
    float* out = (float*)d_out;
    float* ws  = (float*)d_ws;    // 2 MB partial for the second K-half

    made_k1<<<dim3(1024), dim3(256), 0, stream>>>(x, state, masks, kern, out, ws);
    made_k2<<<dim3(512),  dim3(256), 0, stream>>>(ws, b0, out);
}

// Round 6
// 26.238 us; speedup vs baseline: 1.4674x; 1.0800x over previous
//
#include <hip/hip_runtime.h>
#include <hip/hip_bf16.h>

// MaskedDenseLayer round 6: two-pass design exploiting BINARY masks.
//
// Pass 1 (made_pre, streaming, HBM-bound):
//   - mbits: masks (51.4 MB f32 of exact 0.0/1.0) -> 1 bit each, laid out
//     [s][ot][q][t][lane] u8 so the main loop reads one coalesced 64B row.
//   - kern_q: kern -> bf16 in MFMA-step-major layout [ot][q][t][lane][8 bf16],
//     so the main loop's B-source is ONE coalesced 1KB dwordx4 per step.
//   - xt: x -> bf16 [512][784].
// Pass 2 (made_main): grouped GEMM, NO barriers in the K-loop, no f32->bf16
//   on the B path: B-frag = kern_q dwordx4 AND bit-expanded mask. A-frags
//   (13 x bf16x8 = 52 VGPR) preloaded per wave. 8 waves = 4 K-quarters x
//   2 m-frags; mfma_f32_32x32x16_bf16; one LDS reduce; fused bias+relu.
// K = 784 = 49 steps of 16, quarters of 13/12/12/12 steps (padded to 13;
// pad slots have bit-byte 0 -> B = 0 exactly; A pad reads clamped in-bounds).

#define IN_DIM 784
#define OUT_DIM 1024
#define BS 512

typedef __attribute__((ext_vector_type(8))) short bf16x8;
typedef __attribute__((ext_vector_type(16))) float f32x16;

// ws layout (ws is ~268 MB; we use < 5 MB)
#define XT_OFF 0u            // bf16 [512][784]              (802,816 B)
#define KQ_OFF (1u << 20)    // 16B slots [32 ot][4 q][13 t][64 lane] (1,703,936 B)
#define MB_OFF (3u << 20)    // u8 [16 s][32 ot][4 q][13 t][64 lane]  (1,703,936 B)

#define NBITS_BLOCKS 6656    // 16*32*13
#define NKERN_BLOCKS 416     // 32*13
#define NXT_BLOCKS   392     // 100352 float4 / 256

static __device__ inline short f2bf(float f) {
    __hip_bfloat16 h = __float2bfloat16(f);   // RNE
    short r; __builtin_memcpy(&r, &h, 2); return r;
}

__global__ __launch_bounds__(256) void made_pre(
    const float* __restrict__ x,      // [512, 784]
    const float* __restrict__ masks,  // [16, 784, 1024]
    const float* __restrict__ kern,   // [784, 1024]
    unsigned char* __restrict__ ws)
{
    const int bid = blockIdx.x, tid = threadIdx.x;
    const int lane = tid & 63;
    const int q    = tid >> 6;               // wave = one K-quarter
    const int l31  = lane & 31, khl = lane >> 5;
    const int stp  = q ? 12 : 13;
    const int qoff = q ? (16 + 192 * q) : 0; // 0,208,400,592

    if (bid < NBITS_BLOCKS) {                // ---- mask -> bits ----
        const int s  = bid / 416;
        const int r  = bid % 416;
        const int ot = r / 13;
        const int t  = r % 13;
        unsigned b = 0;
        if (t < stp) {
            const int kb = qoff + t * 16 + khl * 8;
            const float* mrow = masks + ((size_t)s * IN_DIM + kb) * OUT_DIM + ot * 32 + l31;
#pragma unroll
            for (int e = 0; e < 8; ++e)
                b |= (mrow[e * OUT_DIM] != 0.f ? 1u : 0u) << e;
        }
        ws[MB_OFF + ((((size_t)(s * 32 + ot) * 4 + q) * 13 + t) * 64 + lane)] =
            (unsigned char)b;
    } else if (bid < NBITS_BLOCKS + NKERN_BLOCKS) {   // ---- kern -> bf16 step-major ----
        const int r  = bid - NBITS_BLOCKS;
        const int ot = r / 13;
        const int t  = r % 13;
        bf16x8 kv;
#pragma unroll
        for (int e = 0; e < 8; ++e) kv[e] = 0;
        if (t < stp) {
            const int kb = qoff + t * 16 + khl * 8;
            const float* krow = kern + (size_t)kb * OUT_DIM + ot * 32 + l31;
#pragma unroll
            for (int e = 0; e < 8; ++e) kv[e] = f2bf(krow[e * OUT_DIM]);
        }
        *(bf16x8*)(ws + KQ_OFF + (((size_t)(ot * 4 + q) * 13 + t) * 64 + lane) * 16) = kv;
    } else {                                  // ---- x -> bf16 ----
        const int i = (bid - NBITS_BLOCKS - NKERN_BLOCKS) * 256 + tid;  // float4 idx
        float4 v = ((const float4*)x)[i];
        ushort4 o;
        o.x = (unsigned short)f2bf(v.x);
        o.y = (unsigned short)f2bf(v.y);
        o.z = (unsigned short)f2bf(v.z);
        o.w = (unsigned short)f2bf(v.w);
        ((ushort4*)(ws + XT_OFF))[i] = o;
    }
}

__global__ __launch_bounds__(512, 4) void made_main(
    const int*           __restrict__ state,  // [512]
    const unsigned char* __restrict__ ws,
    const float*         __restrict__ bias,   // [1024]
    float*               __restrict__ out)    // [512, 1024]
{
    __shared__ int   list[BS];
    __shared__ int   cnt;
    __shared__ float red[3][2][16][64];   // [q-1][m][reg][lane] 24 KB

    const int tid  = threadIdx.x;
    const int lane = tid & 63;
    const int w    = tid >> 6;
    const int q    = w & 3;               // K-quarter
    const int m    = w >> 2;              // m-frag (rows m*32..m*32+31)
    const int s    = blockIdx.x & 15;
    const int ot   = blockIdx.x >> 4;

    if (tid == 0) cnt = 0;
    __syncthreads();
    { int st = state[tid]; if (st == s) { int p = atomicAdd(&cnt, 1); list[p] = tid; } }
    __syncthreads();
    const int ns = cnt;
    if (ns == 0) return;                  // block-uniform

    const int l31 = lane & 31, khl = lane >> 5;
    const int qoff = q ? (16 + 192 * q) : 0;

    // ---- A preload: 13 bf16x8 frags from this lane's gathered x row ----
    int ridx = m * 32 + l31; if (ridx >= ns) ridx = ns - 1;
    const unsigned short* xrow =
        (const unsigned short*)(ws + XT_OFF) + (size_t)list[ridx] * IN_DIM;
    bf16x8 a[13];
#pragma unroll
    for (int t = 0; t < 13; ++t) {
        // pad step (q>0, t==12): B is exactly 0; re-read a safe offset so A
        // stays finite (0 * finite == 0).
        const int off = (q && t == 12) ? qoff : qoff + t * 16;
        a[t] = *(const bf16x8*)(xrow + off + khl * 8);
    }

    // ---- K-loop: coalesced kern frag + bit-expand, no barriers ----
    const uint4* kp = (const uint4*)(ws + KQ_OFF) + ((size_t)(ot * 4 + q) * 13) * 64 + lane;
    const unsigned char* bp = ws + MB_OFF + (((size_t)(s * 32 + ot) * 4 + q) * 13) * 64 + lane;

    f32x16 acc;
#pragma unroll
    for (int r = 0; r < 16; ++r) acc[r] = 0.f;

#pragma unroll
    for (int t = 0; t < 13; ++t) {
        uint4 kv = kp[t * 64];
        unsigned bb = bp[t * 64];
        uint4 bv;
        bv.x = kv.x & ((bb &   1u ? 0xFFFFu : 0u) | (bb &   2u ? 0xFFFF0000u : 0u));
        bv.y = kv.y & ((bb &   4u ? 0xFFFFu : 0u) | (bb &   8u ? 0xFFFF0000u : 0u));
        bv.z = kv.z & ((bb &  16u ? 0xFFFFu : 0u) | (bb &  32u ? 0xFFFF0000u : 0u));
        bv.w = kv.w & ((bb &  64u ? 0xFFFFu : 0u) | (bb & 128u ? 0xFFFF0000u : 0u));
        bf16x8 bfr; __builtin_memcpy(&bfr, &bv, 16);
        acc = __builtin_amdgcn_mfma_f32_32x32x16_bf16(a[t], bfr, acc, 0, 0, 0);
    }

    // ---- reduce 4 K-quarters, fused bias+relu store ----
    if (q) {
#pragma unroll
        for (int j = 0; j < 16; ++j) red[q - 1][m][j][lane] = acc[j];
    }
    __syncthreads();
    if (q == 0) {
        const float bv = bias[ot * 32 + l31];
#pragma unroll
        for (int j = 0; j < 16; ++j) {
            float v = acc[j] + red[0][m][j][lane] + red[1][m][j][lane] + red[2][m][j][lane];
            const int row = (j & 3) + 8 * (j >> 2) + 4 * khl;   // C/D layout (m74/m101)
            const int sr  = m * 32 + row;
            if (sr < ns) {
                float o = v + bv;
                out[(size_t)list[sr] * OUT_DIM + ot * 32 + l31] = o > 0.f ? o : 0.f;
            }
        }
    }
}

extern "C" void kernel_launch(void* const* d_in, const int* in_sizes, int n_in,
                              void* d_out, int out_size, void* d_ws, size_t ws_size,
                              hipStream_t stream) {
    (void)in_sizes; (void)n_in; (void)out_size; (void)ws_size;
    const float* x     = (const float*)d_in[0];
    const int*   state = (const int*)  d_in[1];
    const float* masks = (const float*)d_in[2];
    const float* kern  = (const float*)d_in[3];
    const float* b0    = (const float*)d_in[4];
    float* out = (float*)d_out;
    unsigned char* ws = (unsigned char*)d_ws;

    made_pre<<<dim3(NBITS_BLOCKS + NKERN_BLOCKS + NXT_BLOCKS), dim3(256), 0, stream>>>(
        x, masks, kern, ws);
    made_main<<<dim3(512), dim3(512), 0, stream>>>(state, ws, b0, out);
}